// Round 7
// baseline (189.100 us; speedup 1.0000x reference)
//
#include <hip/hip_runtime.h>

#define NB 128
#define NC 12
#define NL 1024
#define NDIL 7
#define NDIV 2
#define NH 32
#define NK 8
#define NKSZ 9
#define NNCP 6
#define OUTPB (NDIL*NDIV*2*NH*NK)   // 7168

// LDS: [Z0 256][g0 1024][Z1 256][g1 1024][Z2 256][g2 1024][Z3 256][g3 1024][Z4 256]
// zero strips shared between adjacent waves' pads; wave w zeroes strips w and w+1.
#define SER_STRIDE 1280
#define LDS_FLOATS (4*SER_STRIDE + 256)   // 5376 floats = 21504 B

typedef __fp16 h2 __attribute__((ext_vector_type(2)));

__device__ __forceinline__ float4 ld4(const float* p) { return *(const float4*)p; }

__device__ __forceinline__ float sgpr_f(float v) {
    return __int_as_float(__builtin_amdgcn_readfirstlane(__float_as_int(v)));
}
__device__ __forceinline__ h2 sgpr_h2(h2 v) {
    int i = __builtin_amdgcn_readfirstlane(__builtin_bit_cast(int, v));
    return __builtin_bit_cast(h2, i);
}
__device__ __forceinline__ h2 pkrtz(float x, float y) {
    return __builtin_amdgcn_cvt_pkrtz(x, y);
}
__device__ __forceinline__ float dot2(h2 a, h2 b, float c) {
    return __builtin_amdgcn_fdot2(a, b, c, false);
}

template<int CTRL, int RM>
__device__ __forceinline__ float dppadd_f(float x) {
    int t = __builtin_amdgcn_update_dpp(0, __float_as_int(x), CTRL, RM, 0xf, false);
    return x + __int_as_float(t);
}
template<int CTRL, int RM>
__device__ __forceinline__ unsigned dppadd_u(unsigned x) {
    int t = __builtin_amdgcn_update_dpp(0, (int)x, CTRL, RM, 0xf, false);
    return x + (unsigned)t;
}
// full-wave sum; result valid on lane 63
#define RSUM_F(x) { x = dppadd_f<0x111,0xf>(x); x = dppadd_f<0x112,0xf>(x); \
                    x = dppadd_f<0x114,0xf>(x); x = dppadd_f<0x118,0xf>(x); \
                    x = dppadd_f<0x142,0xa>(x); x = dppadd_f<0x143,0xc>(x); }
#define RSUM_U(x) { x = dppadd_u<0x111,0xf>(x); x = dppadd_u<0x112,0xf>(x); \
                    x = dppadd_u<0x114,0xf>(x); x = dppadd_u<0x118,0xf>(x); \
                    x = dppadd_u<0x142,0xa>(x); x = dppadd_u<0x143,0xc>(x); }

__global__ __launch_bounds__(256) void hydra_kernel(
    const float* __restrict__ X,   // [B, C, L]
    const float* __restrict__ W,   // [NDIL, NDIV, K*H, 1, KSZ]
    const int*   __restrict__ I,   // [NDIL, NDIV, H, NCP]
    float*       __restrict__ out) // [B, 28*H*K]
{
    __shared__ float lds[LDS_FLOATS];

    const int bid = blockIdx.x;
    const int h4 = bid & 7;
    const int dj = (bid >> 3) % 14;
    const int b  = (bid >> 3) / 14;
    const int di = dj >> 1;
    const int j  = dj & 1;
    const int d  = 1 << di;

    const int tid  = threadIdx.x;
    const int lane = tid & 63;
    const int wid  = __builtin_amdgcn_readfirstlane(tid >> 6);
    const int h    = h4 * 4 + wid;            // wave-uniform
    const int Sw   = 256 + wid * SER_STRIDE;  // this wave's series base

    // zero own pad strips (w and w+1); neighbor duplicate zero-writes benign
    #pragma unroll
    for (int z = 0; z < 2; ++z) {
        float4 zz; zz.x = 0.f; zz.y = 0.f; zz.z = 0.f; zz.w = 0.f;
        *(float4*)(lds + (wid + z) * SER_STRIDE + 4 * lane) = zz;
    }

    // --- gather-sum into this wave's series (wave-private, no barrier) ----
    const int* idx = I + ((di*NDIV + j)*NH + h)*NNCP;
    const float* xb = X + (size_t)b * NC * NL;
    const float* p0 = xb + idx[0]*NL;
    const float* p1 = xb + idx[1]*NL;
    const float* p2 = xb + idx[2]*NL;
    const float* p3 = xb + idx[3]*NL;
    const float* p4 = xb + idx[4]*NL;
    const float* p5 = xb + idx[5]*NL;

    if (j == 0) {
        #pragma unroll
        for (int c = 0; c < 4; ++c) {
            const int e = 256*c + 4*lane;
            float4 v0 = ld4(p0+e), v1 = ld4(p1+e), v2 = ld4(p2+e);
            float4 v3 = ld4(p3+e), v4 = ld4(p4+e), v5 = ld4(p5+e);
            float4 s;
            s.x = v0.x+v1.x+v2.x+v3.x+v4.x+v5.x;
            s.y = v0.y+v1.y+v2.y+v3.y+v4.y+v5.y;
            s.z = v0.z+v1.z+v2.z+v3.z+v4.z+v5.z;
            s.w = v0.w+v1.w+v2.w+v3.w+v4.w+v5.w;
            *(float4*)(lds + Sw + e) = s;
        }
    } else {
        // diff-of-gather == gather-of-diff (linearity)
        float4 sa[4];
        #pragma unroll
        for (int c = 0; c < 4; ++c) {
            const int e = 256*c + 4*lane;
            float4 v0 = ld4(p0+e), v1 = ld4(p1+e), v2 = ld4(p2+e);
            float4 v3 = ld4(p3+e), v4 = ld4(p4+e), v5 = ld4(p5+e);
            sa[c].x = v0.x+v1.x+v2.x+v3.x+v4.x+v5.x;
            sa[c].y = v0.y+v1.y+v2.y+v3.y+v4.y+v5.y;
            sa[c].z = v0.z+v1.z+v2.z+v3.z+v4.z+v5.z;
            sa[c].w = v0.w+v1.w+v2.w+v3.w+v4.w+v5.w;
        }
        #pragma unroll
        for (int c = 0; c < 4; ++c) {
            const float nxt = (c < 3) ? __shfl(sa[(c+1) & 3].x, 0, 64) : 0.f;
            const float sh  = __shfl_down(sa[c].x, 1, 64);
            const float Se4 = (lane == 63) ? nxt : sh;
            float4 df;
            df.x = sa[c].y - sa[c].x;
            df.y = sa[c].z - sa[c].y;
            df.z = sa[c].w - sa[c].z;
            df.w = Se4 - sa[c].w;
            if (c == 3 && lane == 63) df.w = 0.f;   // diff series: slot 1023 = 0
            const int e = 256*c + 4*lane;
            *(float4*)(lds + Sw + e) = df;
        }
    }

    // --- weights: packed f16 pairs + last tap f32, all in SGPRs -----------
    h2    wp[NK][4];   // taps (0,1),(2,3),(4,5),(6,7)
    float w8[NK];      // tap 8
    {
        const float* Wp = W + (size_t)((di*NDIV + j)*(NK*NH) + h*NK) * NKSZ;
        #pragma unroll
        for (int k = 0; k < NK; ++k) {
            #pragma unroll
            for (int t = 0; t < 4; ++t)
                wp[k][t] = sgpr_h2(pkrtz(Wp[k*NKSZ + 2*t], Wp[k*NKSZ + 2*t + 1]));
            w8[k] = sgpr_f(Wp[k*NKSZ + 8]);
        }
    }

    float    cm[NK];
    unsigned cn[NK];
    #pragma unroll
    for (int k = 0; k < NK; ++k) { cm[k] = 0.f; cn[k] = 0u; }

    const int  base = Sw + 2*lane;               // pos-pair index in lds
    const bool okl  = (j == 0) || (lane != 63);  // only pos 1023/j=1 invalid

#define ARGBIN(A, OK)                                                     \
    {                                                                     \
        float mx = fmaxf(fmaxf(A[0], A[1]), A[2]);                        \
        mx = fmaxf(fmaxf(mx, A[3]), A[4]);                                \
        mx = fmaxf(fmaxf(mx, A[5]), A[6]);                                \
        mx = fmaxf(mx, A[7]);                                             \
        float mn = fminf(fminf(A[0], A[1]), A[2]);                        \
        mn = fminf(fminf(mn, A[3]), A[4]);                                \
        mn = fminf(fminf(mn, A[5]), A[6]);                                \
        mn = fminf(mn, A[7]);                                             \
        if (OK) {                                                         \
            _Pragma("unroll")                                             \
            for (int k = 0; k < NK; ++k) {                                \
                cm[k] += (A[k] == mx) ? A[k] : 0.f;                       \
                cn[k] += (A[k] == mn) ? 1u : 0u;                          \
            }                                                             \
        }                                                                 \
    }

    if (d == 1) {
        for (int c = 0; c < 8; ++c) {
            const float* bp = lds + base - 4 + 128*c;
            float2 q0 = *(const float2*)(bp);
            float2 q1 = *(const float2*)(bp + 2);
            float2 q2 = *(const float2*)(bp + 4);
            float2 q3 = *(const float2*)(bp + 6);
            float2 q4 = *(const float2*)(bp + 8);
            const float win[10] = { q0.x,q0.y,q1.x,q1.y,q2.x,q2.y,q3.x,q3.y,q4.x,q4.y };
            // packed pairs starting at offset i: (win[i], win[i+1])
            h2 pk[8];
            #pragma unroll
            for (int i = 0; i < 8; ++i) pk[i] = pkrtz(win[i], win[i+1]);
            float a0[NK], a1[NK];
            #pragma unroll
            for (int k = 0; k < NK; ++k) {
                a0[k] = dot2(wp[k][0], pk[0], 0.f);
                a0[k] = dot2(wp[k][1], pk[2], a0[k]);
                a0[k] = dot2(wp[k][2], pk[4], a0[k]);
                a0[k] = dot2(wp[k][3], pk[6], a0[k]);
                a0[k] = fmaf(w8[k], win[8], a0[k]);
                a1[k] = dot2(wp[k][0], pk[1], 0.f);
                a1[k] = dot2(wp[k][1], pk[3], a1[k]);
                a1[k] = dot2(wp[k][2], pk[5], a1[k]);
                a1[k] = dot2(wp[k][3], pk[7], a1[k]);
                a1[k] = fmaf(w8[k], win[9], a1[k]);
            }
            ARGBIN(a0, true);
            ARGBIN(a1, (c != 7) || okl);
        }
    } else {
        for (int c = 0; c < 8; ++c) {
            float2 r[NKSZ];
            #pragma unroll
            for (int t = 0; t < NKSZ; ++t)
                r[t] = *(const float2*)(lds + base + (t - 4)*d + 128*c);
            // pack tap-pairs per position
            h2 pa[4], pb[4];
            #pragma unroll
            for (int tp = 0; tp < 4; ++tp) {
                pa[tp] = pkrtz(r[2*tp].x, r[2*tp+1].x);
                pb[tp] = pkrtz(r[2*tp].y, r[2*tp+1].y);
            }
            float a0[NK], a1[NK];
            #pragma unroll
            for (int k = 0; k < NK; ++k) {
                a0[k] = dot2(wp[k][0], pa[0], 0.f);
                a0[k] = dot2(wp[k][1], pa[1], a0[k]);
                a0[k] = dot2(wp[k][2], pa[2], a0[k]);
                a0[k] = dot2(wp[k][3], pa[3], a0[k]);
                a0[k] = fmaf(w8[k], r[8].x, a0[k]);
                a1[k] = dot2(wp[k][0], pb[0], 0.f);
                a1[k] = dot2(wp[k][1], pb[1], a1[k]);
                a1[k] = dot2(wp[k][2], pb[2], a1[k]);
                a1[k] = dot2(wp[k][3], pb[3], a1[k]);
                a1[k] = fmaf(w8[k], r[8].y, a1[k]);
            }
            ARGBIN(a0, true);
            ARGBIN(a1, (c != 7) || okl);
        }
    }
#undef ARGBIN

    // pack counts (each half-word sum <= 1024, no carry crossing)
    unsigned cp[4];
    #pragma unroll
    for (int i = 0; i < 4; ++i) cp[i] = cn[2*i] | (cn[2*i+1] << 16);

    // DPP wave sums (VALU-only), results land on lane 63
    #pragma unroll
    for (int k = 0; k < NK; ++k) RSUM_F(cm[k]);
    #pragma unroll
    for (int i = 0; i < 4; ++i) RSUM_U(cp[i]);

    // lane 63 writes this wave's 16 outputs directly (no barrier, no LDS)
    if (lane == 63) {
        float* ob = out + (size_t)b*OUTPB + (dj*2)*(NH*NK) + h*NK;
        #pragma unroll
        for (int k = 0; k < NK; ++k) ob[k] = cm[k];
        float* oc = ob + NH*NK;
        #pragma unroll
        for (int i = 0; i < 4; ++i) {
            oc[2*i]     = (float)(cp[i] & 0xffffu);
            oc[2*i + 1] = (float)(cp[i] >> 16);
        }
    }
}

extern "C" void kernel_launch(void* const* d_in, const int* in_sizes, int n_in,
                              void* d_out, int out_size, void* d_ws, size_t ws_size,
                              hipStream_t stream) {
    const float* X = (const float*)d_in[0];
    const float* W = (const float*)d_in[1];
    const int*   I = (const int*)d_in[2];
    float* out = (float*)d_out;

    const int nblocks = NB * (NDIL*NDIV) * (NH/4);   // 14336
    hydra_kernel<<<dim3(nblocks), dim3(256), 0, stream>>>(X, W, I, out);
}

// Round 8
// 159.128 us; speedup vs baseline: 1.1883x; 1.1883x over previous
//
#include <hip/hip_runtime.h>

#define NB 128
#define NC 12
#define NL 1024
#define NDIL 7
#define NDIV 2
#define NH 32
#define NK 8
#define NKSZ 9
#define NNCP 6
#define OUTPB (NDIL*NDIV*2*NH*NK)   // 7168

// LDS: [Z0 256][g0 1024][Z1 256][g1 1024][Z2 256][g2 1024][Z3 256][g3 1024][Z4 256]
// zero strips shared between adjacent waves' pads; wave w zeroes strips w and w+1.
#define SER_STRIDE 1280
#define LDS_FLOATS (4*SER_STRIDE + 256)   // 5376 floats = 21504 B

__device__ __forceinline__ float4 ld4(const float* p) { return *(const float4*)p; }

__device__ __forceinline__ float sgpr_f(float v) {
    return __int_as_float(__builtin_amdgcn_readfirstlane(__float_as_int(v)));
}

template<int CTRL, int RM>
__device__ __forceinline__ float dppadd_f(float x) {
    int t = __builtin_amdgcn_update_dpp(0, __float_as_int(x), CTRL, RM, 0xf, false);
    return x + __int_as_float(t);
}
template<int CTRL, int RM>
__device__ __forceinline__ unsigned dppadd_u(unsigned x) {
    int t = __builtin_amdgcn_update_dpp(0, (int)x, CTRL, RM, 0xf, false);
    return x + (unsigned)t;
}
// full-wave sum; result valid on lane 63
#define RSUM_F(x) { x = dppadd_f<0x111,0xf>(x); x = dppadd_f<0x112,0xf>(x); \
                    x = dppadd_f<0x114,0xf>(x); x = dppadd_f<0x118,0xf>(x); \
                    x = dppadd_f<0x142,0xa>(x); x = dppadd_f<0x143,0xc>(x); }
#define RSUM_U(x) { x = dppadd_u<0x111,0xf>(x); x = dppadd_u<0x112,0xf>(x); \
                    x = dppadd_u<0x114,0xf>(x); x = dppadd_u<0x118,0xf>(x); \
                    x = dppadd_u<0x142,0xa>(x); x = dppadd_u<0x143,0xc>(x); }

#define Wk(k,t) wf[(k)*NKSZ+(t)]

#define ARGBIN(A, OK)                                                     \
    {                                                                     \
        float mx = fmaxf(fmaxf(A[0], A[1]), A[2]);                        \
        mx = fmaxf(fmaxf(mx, A[3]), A[4]);                                \
        mx = fmaxf(fmaxf(mx, A[5]), A[6]);                                \
        mx = fmaxf(mx, A[7]);                                             \
        float mn = fminf(fminf(A[0], A[1]), A[2]);                        \
        mn = fminf(fminf(mn, A[3]), A[4]);                                \
        mn = fminf(fminf(mn, A[5]), A[6]);                                \
        mn = fminf(mn, A[7]);                                             \
        if (OK) {                                                         \
            _Pragma("unroll")                                             \
            for (int k = 0; k < NK; ++k) {                                \
                cm[k] += (A[k] == mx) ? A[k] : 0.f;                       \
                cn[k] += (A[k] == mn) ? 1u : 0u;                          \
            }                                                             \
        }                                                                 \
    }

// conv + argbin over 1024 positions (2 per lane per chunk), compile-time dilation D.
// bp0 = lds + Sw + 2*lane. All tap offsets are non-negative imm after -4*D shift.
template<int D>
__device__ __forceinline__ void conv_body(const float* __restrict__ bp0,
                                          const float (&wf)[NK*NKSZ], bool okl,
                                          float (&cm)[NK], unsigned (&cn)[NK]) {
    if constexpr (D == 1) {
        const float* bp = bp0 - 4;
        for (int c = 0; c < 8; ++c, bp += 128) {
            float2 q0 = *(const float2*)(bp);
            float2 q1 = *(const float2*)(bp + 2);
            float2 q2 = *(const float2*)(bp + 4);
            float2 q3 = *(const float2*)(bp + 6);
            float2 q4 = *(const float2*)(bp + 8);
            const float win[10] = { q0.x,q0.y,q1.x,q1.y,q2.x,q2.y,q3.x,q3.y,q4.x,q4.y };
            float a0[NK], a1[NK];
            #pragma unroll
            for (int k = 0; k < NK; ++k) { a0[k] = 0.f; a1[k] = 0.f; }
            #pragma unroll
            for (int t = 0; t < NKSZ; ++t)
                #pragma unroll
                for (int k = 0; k < NK; ++k) {
                    a0[k] = fmaf(Wk(k,t), win[t],   a0[k]);
                    a1[k] = fmaf(Wk(k,t), win[t+1], a1[k]);
                }
            ARGBIN(a0, true);
            ARGBIN(a1, (c != 7) || okl);
        }
    } else {
        const float* bp = bp0 - 4*D;
        for (int c = 0; c < 8; ++c, bp += 128) {
            float2 r[NKSZ];
            #pragma unroll
            for (int t = 0; t < NKSZ; ++t)
                r[t] = *(const float2*)(bp + t*D);   // byte off t*D*4 <= 2048, imm-foldable
            float a0[NK], a1[NK];
            #pragma unroll
            for (int k = 0; k < NK; ++k) { a0[k] = 0.f; a1[k] = 0.f; }
            #pragma unroll
            for (int t = 0; t < NKSZ; ++t)
                #pragma unroll
                for (int k = 0; k < NK; ++k) {
                    a0[k] = fmaf(Wk(k,t), r[t].x, a0[k]);
                    a1[k] = fmaf(Wk(k,t), r[t].y, a1[k]);
                }
            ARGBIN(a0, true);
            ARGBIN(a1, (c != 7) || okl);
        }
    }
}

__global__ __launch_bounds__(256) void hydra_kernel(
    const float* __restrict__ X,   // [B, C, L]
    const float* __restrict__ W,   // [NDIL, NDIV, K*H, 1, KSZ]
    const int*   __restrict__ I,   // [NDIL, NDIV, H, NCP]
    float*       __restrict__ out) // [B, 28*H*K]
{
    __shared__ float lds[LDS_FLOATS];

    const int bid = blockIdx.x;
    const int h4 = bid & 7;
    const int dj = (bid >> 3) % 14;
    const int b  = (bid >> 3) / 14;
    const int di = dj >> 1;
    const int j  = dj & 1;

    const int tid  = threadIdx.x;
    const int lane = tid & 63;
    const int wid  = __builtin_amdgcn_readfirstlane(tid >> 6);
    const int h    = h4 * 4 + wid;            // wave-uniform
    const int Sw   = 256 + wid * SER_STRIDE;  // this wave's series base

    // zero own pad strips (w and w+1); neighbor duplicate zero-writes benign
    #pragma unroll
    for (int z = 0; z < 2; ++z) {
        float4 zz; zz.x = 0.f; zz.y = 0.f; zz.z = 0.f; zz.w = 0.f;
        *(float4*)(lds + (wid + z) * SER_STRIDE + 4 * lane) = zz;
    }

    // --- gather-sum into this wave's series (wave-private, no barrier) ----
    const int* idx = I + ((di*NDIV + j)*NH + h)*NNCP;
    const float* xb = X + (size_t)b * NC * NL;
    const float* p0 = xb + idx[0]*NL;
    const float* p1 = xb + idx[1]*NL;
    const float* p2 = xb + idx[2]*NL;
    const float* p3 = xb + idx[3]*NL;
    const float* p4 = xb + idx[4]*NL;
    const float* p5 = xb + idx[5]*NL;

    if (j == 0) {
        #pragma unroll
        for (int c = 0; c < 4; ++c) {
            const int e = 256*c + 4*lane;
            float4 v0 = ld4(p0+e), v1 = ld4(p1+e), v2 = ld4(p2+e);
            float4 v3 = ld4(p3+e), v4 = ld4(p4+e), v5 = ld4(p5+e);
            float4 s;
            s.x = v0.x+v1.x+v2.x+v3.x+v4.x+v5.x;
            s.y = v0.y+v1.y+v2.y+v3.y+v4.y+v5.y;
            s.z = v0.z+v1.z+v2.z+v3.z+v4.z+v5.z;
            s.w = v0.w+v1.w+v2.w+v3.w+v4.w+v5.w;
            *(float4*)(lds + Sw + e) = s;
        }
    } else {
        // diff-of-gather == gather-of-diff (linearity)
        float4 sa[4];
        #pragma unroll
        for (int c = 0; c < 4; ++c) {
            const int e = 256*c + 4*lane;
            float4 v0 = ld4(p0+e), v1 = ld4(p1+e), v2 = ld4(p2+e);
            float4 v3 = ld4(p3+e), v4 = ld4(p4+e), v5 = ld4(p5+e);
            sa[c].x = v0.x+v1.x+v2.x+v3.x+v4.x+v5.x;
            sa[c].y = v0.y+v1.y+v2.y+v3.y+v4.y+v5.y;
            sa[c].z = v0.z+v1.z+v2.z+v3.z+v4.z+v5.z;
            sa[c].w = v0.w+v1.w+v2.w+v3.w+v4.w+v5.w;
        }
        #pragma unroll
        for (int c = 0; c < 4; ++c) {
            const float nxt = (c < 3) ? __shfl(sa[(c+1) & 3].x, 0, 64) : 0.f;
            const float sh  = __shfl_down(sa[c].x, 1, 64);
            const float Se4 = (lane == 63) ? nxt : sh;
            float4 df;
            df.x = sa[c].y - sa[c].x;
            df.y = sa[c].z - sa[c].y;
            df.z = sa[c].w - sa[c].z;
            df.w = Se4 - sa[c].w;
            if (c == 3 && lane == 63) df.w = 0.f;   // diff series: slot 1023 = 0
            const int e = 256*c + 4*lane;
            *(float4*)(lds + Sw + e) = df;
        }
    }

    // --- weights: force into SGPRs (wave-uniform h) -----------------------
    float wf[NK*NKSZ];
    {
        const float* Wp = W + (size_t)((di*NDIV + j)*(NK*NH) + h*NK) * NKSZ;
        #pragma unroll
        for (int i = 0; i < 18; ++i) {
            float4 v = ld4(Wp + 4*i);
            wf[4*i+0] = sgpr_f(v.x); wf[4*i+1] = sgpr_f(v.y);
            wf[4*i+2] = sgpr_f(v.z); wf[4*i+3] = sgpr_f(v.w);
        }
    }

    float    cm[NK];
    unsigned cn[NK];
    #pragma unroll
    for (int k = 0; k < NK; ++k) { cm[k] = 0.f; cn[k] = 0u; }

    const float* bp0 = lds + Sw + 2*lane;        // pos-pair base
    const bool   okl = (j == 0) || (lane != 63); // only pos 1023/j=1 invalid

    switch (di) {
        case 0: conv_body<1>( bp0, wf, okl, cm, cn); break;
        case 1: conv_body<2>( bp0, wf, okl, cm, cn); break;
        case 2: conv_body<4>( bp0, wf, okl, cm, cn); break;
        case 3: conv_body<8>( bp0, wf, okl, cm, cn); break;
        case 4: conv_body<16>(bp0, wf, okl, cm, cn); break;
        case 5: conv_body<32>(bp0, wf, okl, cm, cn); break;
        default: conv_body<64>(bp0, wf, okl, cm, cn); break;
    }

    // pack counts (each half-word sum <= 1024, no carry crossing)
    unsigned cp[4];
    #pragma unroll
    for (int i = 0; i < 4; ++i) cp[i] = cn[2*i] | (cn[2*i+1] << 16);

    // DPP wave sums (VALU-only), results land on lane 63
    #pragma unroll
    for (int k = 0; k < NK; ++k) RSUM_F(cm[k]);
    #pragma unroll
    for (int i = 0; i < 4; ++i) RSUM_U(cp[i]);

    // lane 63 writes this wave's 16 outputs directly (no barrier, no LDS)
    if (lane == 63) {
        float* ob = out + (size_t)b*OUTPB + (dj*2)*(NH*NK) + h*NK;
        #pragma unroll
        for (int k = 0; k < NK; ++k) ob[k] = cm[k];
        float* oc = ob + NH*NK;
        #pragma unroll
        for (int i = 0; i < 4; ++i) {
            oc[2*i]     = (float)(cp[i] & 0xffffu);
            oc[2*i + 1] = (float)(cp[i] >> 16);
        }
    }
}

extern "C" void kernel_launch(void* const* d_in, const int* in_sizes, int n_in,
                              void* d_out, int out_size, void* d_ws, size_t ws_size,
                              hipStream_t stream) {
    const float* X = (const float*)d_in[0];
    const float* W = (const float*)d_in[1];
    const int*   I = (const int*)d_in[2];
    float* out = (float*)d_out;

    const int nblocks = NB * (NDIL*NDIV) * (NH/4);   // 14336
    hydra_kernel<<<dim3(nblocks), dim3(256), 0, stream>>>(X, W, I, out);
}